// Round 5
// baseline (397.433 us; speedup 1.0000x reference)
//
#include <hip/hip_runtime.h>
#include <cstddef>

// Problem constants
#define NB 128    // B
#define NT 64     // N0 (time/positions)
#define ND 32     // D0 == D1
#define NG 64     // N1 (groups/capsules)
#define NC 2048   // N1*D1 channels
#define KW 65     // conv kernel size
#define EPSZ 1.1920928955078125e-07f

// ws layout (floats)
#define OFF_URAW 0ull
#define SZ_URAW  (3ull * NB * NT * NC)
#define OFF_F    (OFF_URAW + SZ_URAW)
#define SZ_F     (3ull * NB * NC)
#define OFF_S1   (OFF_F + SZ_F)
#define SZ_S1    ((unsigned long long)NB * NT)
#define OFF_KV   (OFF_S1 + SZ_S1)
#define SZ_KV    ((unsigned long long)NB * NT * NT)
// overlays:
//   pre[b][ch][jj]  -> u2 region (dead after k_kv)
//   cwt[o][ci*64+jj]-> u3 region (dead after k_kv)
//   ysum[b][o]      -> u1 region start (dead after k_pre), zeroed after k_pre

// ---------------------------------------------------------------------------
// K1: transform. For each j (0..63) a GEMM  [384 rows=(inp,b)] x [32 i] x [2048 c]
// writes u_raw[inp][b][t=j][ch=c]
// ---------------------------------------------------------------------------
__global__ __launch_bounds__(256) void k_transform(
    const float* __restrict__ x1, const float* __restrict__ x2,
    const float* __restrict__ x3, const float* __restrict__ W,
    float* __restrict__ uraw) {
  int bid = blockIdx.x;
  int j   = bid & 63;
  int nt  = (bid >> 6) & 15;
  int inp = bid >> 10;
  const float* x = (inp == 0) ? x1 : ((inp == 1) ? x2 : x3);
  float* uout = uraw + (size_t)inp * ((size_t)NB * NT * NC);

  __shared__ float as[32][132];  // [i][b]
  __shared__ float bs[32][132];  // [i][c_local]
  int tid = threadIdx.x;

  { // A tile: x[b][j][i]  -> as[i][b]
    int b = tid >> 1, h = tid & 1;
    const float* xp = x + ((size_t)b * NT + j) * ND + h * 16;
#pragma unroll
    for (int q = 0; q < 4; ++q) {
      float4 v = *reinterpret_cast<const float4*>(xp + q * 4);
      int i0 = h * 16 + q * 4;
      as[i0 + 0][b] = v.x; as[i0 + 1][b] = v.y;
      as[i0 + 2][b] = v.z; as[i0 + 3][b] = v.w;
    }
  }
  { // B tile: W[k0+kk][j][i][z] -> bs[i][kk*32+z]
    int kk = tid >> 6, u = tid & 63;
    int i = u >> 1, h = u & 1;
    const float* wp = W + (((size_t)(nt * 4 + kk) * NT + j) * ND + i) * ND + h * 16;
#pragma unroll
    for (int q = 0; q < 4; ++q) {
      float4 v = *reinterpret_cast<const float4*>(wp + q * 4);
      int c0 = kk * 32 + h * 16 + q * 4;
      bs[i][c0 + 0] = v.x; bs[i][c0 + 1] = v.y;
      bs[i][c0 + 2] = v.z; bs[i][c0 + 3] = v.w;
    }
  }
  __syncthreads();

  int tm = tid & 15, tn = tid >> 4;
  int m0 = tm * 8, n0 = tn * 8;
  float acc[8][8];
#pragma unroll
  for (int a = 0; a < 8; ++a)
#pragma unroll
    for (int c = 0; c < 8; ++c) acc[a][c] = 0.f;

#pragma unroll 4
  for (int kk = 0; kk < 32; ++kk) {
    float4 a0 = *reinterpret_cast<const float4*>(&as[kk][m0]);
    float4 a1 = *reinterpret_cast<const float4*>(&as[kk][m0 + 4]);
    float4 b0 = *reinterpret_cast<const float4*>(&bs[kk][n0]);
    float4 b1 = *reinterpret_cast<const float4*>(&bs[kk][n0 + 4]);
    float av[8] = {a0.x, a0.y, a0.z, a0.w, a1.x, a1.y, a1.z, a1.w};
    float bv[8] = {b0.x, b0.y, b0.z, b0.w, b1.x, b1.y, b1.z, b1.w};
#pragma unroll
    for (int mi = 0; mi < 8; ++mi)
#pragma unroll
      for (int ni = 0; ni < 8; ++ni)
        acc[mi][ni] = fmaf(av[mi], bv[ni], acc[mi][ni]);
  }

#pragma unroll
  for (int mi = 0; mi < 8; ++mi) {
    float* cp = uout + ((size_t)(m0 + mi) * NT + j) * NC + nt * 128 + n0;
    float4 v0 = {acc[mi][0], acc[mi][1], acc[mi][2], acc[mi][3]};
    float4 v1 = {acc[mi][4], acc[mi][5], acc[mi][6], acc[mi][7]};
    *reinterpret_cast<float4*>(cp)     = v0;
    *reinterpret_cast<float4*>(cp + 4) = v1;
  }
}

// ---------------------------------------------------------------------------
// K2: focus factors f = sqrt(sum u'^2)/sqrt(sum u'^6), 2 ch per thread.
// For inp==0 also computes s1[b][t] = sum_ch u1'^3 * f (focused row sums).
// grid: inp(3) x b(128) x quarter(4) = 1536 blocks, 256 threads
// ---------------------------------------------------------------------------
__global__ __launch_bounds__(256) void k_factors(
    const float* __restrict__ uraw, float* __restrict__ f,
    float* __restrict__ s1) {
  int bid = blockIdx.x;
  int q = bid & 3, b = (bid >> 2) & 127, inp = bid >> 9;
  const float* u = uraw + ((size_t)inp * NB + b) * ((size_t)NT * NC);
  int tid = threadIdx.x;
  int ch = q * 512 + tid * 2;

  float s2a = 0.f, s6a = 0.f, s2b = 0.f, s6b = 0.f;
  for (int t = 0; t < NT; ++t) {
    float2 v = *reinterpret_cast<const float2*>(u + (size_t)t * NC + ch);
    float ua = (fmaxf(v.x, 0.f) + 1e-6f) * 0.2f;
    float p2a = ua * ua, p3a = p2a * ua;
    s2a += p2a; s6a += p3a * p3a;
    float ub = (fmaxf(v.y, 0.f) + 1e-6f) * 0.2f;
    float p2b = ub * ub, p3b = p2b * ub;
    s2b += p2b; s6b += p3b * p3b;
  }
  float fa = sqrtf(s2a) / sqrtf(s6a);
  float fb = sqrtf(s2b) / sqrtf(s6b);
  float2 fv = {fa, fb};
  *reinterpret_cast<float2*>(f + ((size_t)inp * NB + b) * NC + ch) = fv;

  if (inp == 0) {
    __shared__ float part[NT][4];
    int wid = tid >> 6, lane = tid & 63;
    for (int t = 0; t < NT; ++t) {
      float2 v = *reinterpret_cast<const float2*>(u + (size_t)t * NC + ch);
      float ua = (fmaxf(v.x, 0.f) + 1e-6f) * 0.2f;
      float ub = (fmaxf(v.y, 0.f) + 1e-6f) * 0.2f;
      float val = ua * ua * ua * fa + ub * ub * ub * fb;
#pragma unroll
      for (int m = 32; m >= 1; m >>= 1) val += __shfl_xor(val, m, 64);
      if (lane == 0) part[t][wid] = val;
    }
    __syncthreads();
    if (tid < NT)
      atomicAdd(&s1[b * NT + tid],
                part[tid][0] + part[tid][1] + part[tid][2] + part[tid][3]);
  }
}

// ---------------------------------------------------------------------------
// K3: zero accumulators
// ---------------------------------------------------------------------------
__global__ void k_zero(float* __restrict__ p, int n) {
  int i = blockIdx.x * blockDim.x + threadIdx.x;
  int stride = gridDim.x * blockDim.x;
  for (; i < n; i += stride) p[i] = 0.f;
}

// ---------------------------------------------------------------------------
// K4: kv[b][t1][t2] = sum_ch u2'[t1]*u3'[t2]  (focused), atomic partials.
// grid: b(128) x ch8(8) = 1024 blocks (256 ch each), 256 threads
// ---------------------------------------------------------------------------
__global__ __launch_bounds__(256) void k_kv(
    const float* __restrict__ uraw, const float* __restrict__ f,
    float* __restrict__ kv) {
  int b = blockIdx.x >> 3, chq = blockIdx.x & 7;
  int chbase = chq * 256;
  const float* u2 = uraw + ((size_t)NB + b) * ((size_t)NT * NC);
  const float* u3 = uraw + (2ull * NB + b) * ((size_t)NT * NC);
  const float* f2 = f + ((size_t)NB + b) * NC;
  const float* f3 = f + (2ull * NB + b) * NC;

  __shared__ float a2[64][68];
  __shared__ float a3[64][68];
  int tid = threadIdx.x;

  int tm = tid & 15, tn = tid >> 4;
  float acc[4][4];
#pragma unroll
  for (int r = 0; r < 4; ++r)
#pragma unroll
    for (int q = 0; q < 4; ++q) acc[r][q] = 0.f;

  for (int tile = 0; tile < 4; ++tile) {
    int ch0 = chbase + tile * 64;
    __syncthreads();
    {
      int t = tid >> 2, c4 = tid & 3;
#pragma unroll
      for (int q = 0; q < 4; ++q) {
        int c = c4 * 16 + q * 4;
        float4 v2 = *reinterpret_cast<const float4*>(u2 + (size_t)t * NC + ch0 + c);
        float4 g2 = *reinterpret_cast<const float4*>(f2 + ch0 + c);
        float4 v3 = *reinterpret_cast<const float4*>(u3 + (size_t)t * NC + ch0 + c);
        float4 g3 = *reinterpret_cast<const float4*>(f3 + ch0 + c);
        float vv2[4] = {v2.x, v2.y, v2.z, v2.w};
        float gg2[4] = {g2.x, g2.y, g2.z, g2.w};
        float vv3[4] = {v3.x, v3.y, v3.z, v3.w};
        float gg3[4] = {g3.x, g3.y, g3.z, g3.w};
#pragma unroll
        for (int r = 0; r < 4; ++r) {
          float uu = (fmaxf(vv2[r], 0.f) + 1e-6f) * 0.2f;
          a2[c + r][t] = uu * uu * uu * gg2[r];
          float ww = (fmaxf(vv3[r], 0.f) + 1e-6f) * 0.2f;
          a3[c + r][t] = ww * ww * ww * gg3[r];
        }
      }
    }
    __syncthreads();
#pragma unroll 8
    for (int ch = 0; ch < 64; ++ch) {
      float4 av = *reinterpret_cast<const float4*>(&a2[ch][tm * 4]);
      float4 bv = *reinterpret_cast<const float4*>(&a3[ch][tn * 4]);
      float aa[4] = {av.x, av.y, av.z, av.w};
      float bb[4] = {bv.x, bv.y, bv.z, bv.w};
#pragma unroll
      for (int r = 0; r < 4; ++r)
#pragma unroll
        for (int q = 0; q < 4; ++q)
          acc[r][q] = fmaf(aa[r], bb[q], acc[r][q]);
    }
  }
#pragma unroll
  for (int r = 0; r < 4; ++r)
#pragma unroll
    for (int q = 0; q < 4; ++q)
      atomicAdd(&kv[(size_t)b * (NT * NT) + (tm * 4 + r) * NT + tn * 4 + q],
                acc[r][q]);
}

// ---------------------------------------------------------------------------
// K5: conv-weight transform (prefix-sum domain).
// ---------------------------------------------------------------------------
__global__ __launch_bounds__(64) void k_cwt(
    const float* __restrict__ cw, float* __restrict__ cwt) {
  int o = blockIdx.x;
  int tid = threadIdx.x;
  __shared__ float row[32 * KW];
  for (int i = tid; i < 32 * KW; i += 64) row[i] = cw[(size_t)o * (32 * KW) + i];
  __syncthreads();
  int jj = tid, j = jj + 1;
  for (int ci = 0; ci < 32; ++ci) {
    float v = 0.f;
    if (j <= 32) v -= row[ci * KW + j + 32];
    if (j >= 32 && j <= 63) v += row[ci * KW + j - 32];
    if (j == 64) {
      float s = 0.f;
      for (int k = 32; k <= 64; ++k) s += row[ci * KW + k];
      v += s;
    }
    cwt[(size_t)o * 2048 + ci * 64 + jj] = v;
  }
}

// ---------------------------------------------------------------------------
// K6: pre[b][ch][jj] = z[b,ch] * sum_t1 ut[t1,ch] * kvpre[t1][jj]
// grid: b(128) x ch8(8) = 1024 blocks (256 ch each), 256 threads
// ---------------------------------------------------------------------------
__global__ __launch_bounds__(256) void k_pre(
    const float* __restrict__ uraw, const float* __restrict__ f,
    const float* __restrict__ kvg, const float* __restrict__ s1g,
    float* __restrict__ pre) {
  int b = blockIdx.x >> 3, q = blockIdx.x & 7;
  int chbase = q * 256;
  const float* u1 = uraw + (size_t)b * ((size_t)NT * NC);
  const float* f1 = f + (size_t)b * NC;
  int tid = threadIdx.x;

  __shared__ float kvpreL[64][68];
  __shared__ float s1L[64];
  __shared__ float utL[64][132];   // [t][c4-skewed ch_local], skew c4*33

#pragma unroll
  for (int qq = 0; qq < 16; ++qq) {
    int i = tid + qq * 256;
    kvpreL[i >> 6][i & 63] = kvg[(size_t)b * (NT * NT) + i];
  }
  if (tid < 64) s1L[tid] = s1g[b * NT + tid];
  __syncthreads();
  if (tid < 64) {
    float run = 0.f;
    for (int t2 = 0; t2 < 64; ++t2) {
      run += kvpreL[tid][t2];
      kvpreL[tid][t2] = run;
    }
  }

  int cg = tid >> 3, tg = tid & 7;   // cg: 4-ch group, tg: 8-j group
  for (int tile = 0; tile < 2; ++tile) {
    int ch0 = chbase + tile * 128;
    __syncthreads();
    { // stage focused u1: utL[t][c4*33 + w] = u1'[b][ch0 + c4*32 + w][t]
      int t = tid >> 2, c4 = tid & 3;
      const float* up = u1 + (size_t)t * NC + ch0 + c4 * 32;
      const float* fp = f1 + ch0 + c4 * 32;
#pragma unroll
      for (int qq = 0; qq < 8; ++qq) {
        float4 v  = *reinterpret_cast<const float4*>(up + qq * 4);
        float4 fv = *reinterpret_cast<const float4*>(fp + qq * 4);
        float vv[4] = {v.x, v.y, v.z, v.w};
        float ff[4] = {fv.x, fv.y, fv.z, fv.w};
#pragma unroll
        for (int r = 0; r < 4; ++r) {
          float uu = (fmaxf(vv[r], 0.f) + 1e-6f) * 0.2f;
          utL[t][c4 * 33 + qq * 4 + r] = uu * uu * uu * ff[r];
        }
      }
    }
    __syncthreads();

    int cl = cg * 4;
    int sk = (cl >> 5) * 33 + (cl & 31);
    float acc[4][8];
#pragma unroll
    for (int r = 0; r < 4; ++r)
#pragma unroll
      for (int c = 0; c < 8; ++c) acc[r][c] = 0.f;
    float accz[4] = {0.f, 0.f, 0.f, 0.f};

#pragma unroll 4
    for (int t1 = 0; t1 < 64; ++t1) {
      float4 a = *reinterpret_cast<const float4*>(&utL[t1][sk]);
      float s = s1L[t1];
      float4 k0 = *reinterpret_cast<const float4*>(&kvpreL[t1][tg * 8]);
      float4 k1 = *reinterpret_cast<const float4*>(&kvpreL[t1][tg * 8 + 4]);
      float aa[4] = {a.x, a.y, a.z, a.w};
      float kk[8] = {k0.x, k0.y, k0.z, k0.w, k1.x, k1.y, k1.z, k1.w};
#pragma unroll
      for (int r = 0; r < 4; ++r) {
        accz[r] = fmaf(aa[r], s, accz[r]);
#pragma unroll
        for (int c = 0; c < 8; ++c)
          acc[r][c] = fmaf(aa[r], kk[c], acc[r][c]);
      }
    }
#pragma unroll
    for (int r = 0; r < 4; ++r) {
      float z = 1.f / (accz[r] + EPSZ);
      float* pp = pre + ((size_t)b * NC + ch0 + cl + r) * 64 + tg * 8;
      float4 o0 = {acc[r][0] * z, acc[r][1] * z, acc[r][2] * z, acc[r][3] * z};
      float4 o1 = {acc[r][4] * z, acc[r][5] * z, acc[r][6] * z, acc[r][7] * z};
      *reinterpret_cast<float4*>(pp)     = o0;
      *reinterpret_cast<float4*>(pp + 4) = o1;
    }
  }
}

// ---------------------------------------------------------------------------
// K7: GEMM partials  ysum[b][o] += sum_{K-chunk} cwt[o][K] * pre[b][K]
// grid: g(64) x ks(8) = 512 blocks; block = full 128b x 32o, K=256 (4 ci).
// Transposed LDS tiles -> conflict-free b128 reads, 4b x 4o per thread.
// ---------------------------------------------------------------------------
__global__ __launch_bounds__(256) void k_gemm(
    const float* __restrict__ pre, const float* __restrict__ cwt,
    float* __restrict__ ysum) {
  int g = blockIdx.x >> 3, ks = blockIdx.x & 7;
  int tid = threadIdx.x;
  int oh = tid & 7, bh = tid >> 3;   // o = oh*4+j, b = bh*4+i

  __shared__ float AsT[64][132];  // [jj][b]
  __shared__ float BsT[64][36];   // [jj][o]

  float acc[4][4];
#pragma unroll
  for (int i = 0; i < 4; ++i)
#pragma unroll
    for (int j = 0; j < 4; ++j) acc[i][j] = 0.f;

  for (int kc = 0; kc < 4; ++kc) {
    int ci = ks * 4 + kc;           // capsule-relative input channel
    __syncthreads();
    { // stage A transposed: AsT[jj][b] = pre[b][g*32+ci][jj]
      int bb = tid >> 1, jh = (tid & 1) * 32;
      const float* ap = pre + ((size_t)bb * NC + g * 32 + ci) * 64 + jh;
#pragma unroll
      for (int qq = 0; qq < 8; ++qq) {
        float4 v = *reinterpret_cast<const float4*>(ap + qq * 4);
        int jj = jh + qq * 4;
        AsT[jj + 0][bb] = v.x; AsT[jj + 1][bb] = v.y;
        AsT[jj + 2][bb] = v.z; AsT[jj + 3][bb] = v.w;
      }
    }
    if (tid < 128) { // stage B transposed: BsT[jj][o] = cwt[g*32+o][ci*64+jj]
      int o = tid >> 2, jh = (tid & 3) * 16;
      const float* bp = cwt + (size_t)(g * 32 + o) * 2048 + ci * 64 + jh;
#pragma unroll
      for (int qq = 0; qq < 4; ++qq) {
        float4 v = *reinterpret_cast<const float4*>(bp + qq * 4);
        int jj = jh + qq * 4;
        BsT[jj + 0][o] = v.x; BsT[jj + 1][o] = v.y;
        BsT[jj + 2][o] = v.z; BsT[jj + 3][o] = v.w;
      }
    }
    __syncthreads();

#pragma unroll 8
    for (int jj = 0; jj < 64; ++jj) {
      float4 a = *reinterpret_cast<const float4*>(&AsT[jj][bh * 4]);
      float4 bv = *reinterpret_cast<const float4*>(&BsT[jj][oh * 4]);
      float aa[4] = {a.x, a.y, a.z, a.w};
      float bb[4] = {bv.x, bv.y, bv.z, bv.w};
#pragma unroll
      for (int i = 0; i < 4; ++i)
#pragma unroll
        for (int j = 0; j < 4; ++j)
          acc[i][j] = fmaf(aa[i], bb[j], acc[i][j]);
    }
  }

#pragma unroll
  for (int i = 0; i < 4; ++i)
#pragma unroll
    for (int j = 0; j < 4; ++j)
      atomicAdd(&ysum[(size_t)(bh * 4 + i) * NC + g * 32 + oh * 4 + j],
                acc[i][j]);
}

// ---------------------------------------------------------------------------
// K8: epilogue: val = ysum + xsum(pre[..][63]) + 64*bias; squash over 32-group
// grid: b(128) x gq(8) = 1024 blocks, 256 threads = 8 g x 32 o
// ---------------------------------------------------------------------------
__global__ __launch_bounds__(256) void k_out(
    const float* __restrict__ pre, const float* __restrict__ ysum,
    const float* __restrict__ cb, float* __restrict__ out) {
  int tid = threadIdx.x;
  int b = blockIdx.x >> 3;
  int g = (blockIdx.x & 7) * 8 + (tid >> 5);
  int o = tid & 31;
  int go = g * 32 + o;
  float xs = pre[((size_t)b * NC + go) * 64 + 63];
  float val = ysum[(size_t)b * NC + go] + xs + 64.f * cb[go];
  float sq = val * val;
#pragma unroll
  for (int m = 16; m >= 1; m >>= 1) sq += __shfl_xor(sq, m, 32);
  float norm = sqrtf(sq);
  float coef = 1.f - 1.f / (expf(norm) + 1e-20f);
  out[((size_t)b * NG + g) * ND + o] = coef * val / (norm + 1e-20f);
}

// ---------------------------------------------------------------------------
extern "C" void kernel_launch(void* const* d_in, const int* in_sizes, int n_in,
                              void* d_out, int out_size, void* d_ws, size_t ws_size,
                              hipStream_t stream) {
  const float* x1 = (const float*)d_in[0];
  const float* x2 = (const float*)d_in[1];
  const float* x3 = (const float*)d_in[2];
  const float* W  = (const float*)d_in[3];
  const float* cw = (const float*)d_in[4];
  const float* cb = (const float*)d_in[5];
  float* out = (float*)d_out;

  float* ws   = (float*)d_ws;
  float* uraw = ws + OFF_URAW;
  float* f    = ws + OFF_F;
  float* s1   = ws + OFF_S1;
  float* kv   = ws + OFF_KV;
  // overlays:
  float* pre  = uraw + (size_t)NB * NT * NC;        // u2 region
  float* cwt  = uraw + 2ull * NB * NT * NC;         // u3 region
  float* ysum = uraw;                               // u1 region (dead after k_pre)

  k_transform<<<3072, 256, 0, stream>>>(x1, x2, x3, W, uraw);
  k_zero<<<256, 256, 0, stream>>>(s1, (int)(SZ_S1 + SZ_KV));
  k_factors<<<1536, 256, 0, stream>>>(uraw, f, s1);
  k_kv<<<1024, 256, 0, stream>>>(uraw, f, kv);
  k_cwt<<<2048, 64, 0, stream>>>(cw, cwt);
  k_pre<<<1024, 256, 0, stream>>>(uraw, f, kv, s1, pre);
  k_zero<<<256, 256, 0, stream>>>(ysum, (int)(NB * NC));
  k_gemm<<<512, 256, 0, stream>>>(pre, cwt, ysum);
  k_out<<<1024, 256, 0, stream>>>(pre, ysum, cb, out);
}